// Round 1
// 756.893 us; speedup vs baseline: 32.7567x; 32.7567x over previous
//
#include <hip/hip_runtime.h>
#include <hip/hip_bf16.h>

// Swin block: B=8, H=W=128, C=192, NH=6, HD=32, WS=8, SHIFT=4, N=64, NW=256
// ROUND 7: full MFMA rewrite. All five GEMMs (QKV, QK^T, PV, proj, fc1, fc2)
// use v_mfma_f32_16x16x32_bf16. Weights pre-converted to bf16 in d_ws once.
// Fragment layouts (m89-verified): A row=l&15 k=(l>>4)*8+j; B col=l&15 same k;
// D col=l&15 row=(l>>4)*4+reg. LDS tiles XOR-swizzled (G4) - stride 384B/128B
// is otherwise a 16-way bank conflict on ds_read_b128.

typedef __hip_bfloat16 bf16;
typedef short bf16x8 __attribute__((ext_vector_type(8)));   // 8 bf16 = 4 VGPRs
typedef float f32x4 __attribute__((ext_vector_type(4)));

__device__ __forceinline__ bf16 f2b(float f) { return __float2bfloat16(f); }
__device__ __forceinline__ int lab3(int v) {   // region label along one axis
    return v < 120 ? 0 : (v < 124 ? 1 : 2);    // slices (0,-8),(-8,-4),(-4,None)
}
// swizzled LDS element offset: XOR row low bits into the 16B-block index.
// stride must be a multiple of 64 elements; col stays in its 64-aligned block.
__device__ __forceinline__ int sw(int row, int col, int stride) {
    return row * stride + (col ^ ((row & 7) << 3));
}

// workspace layout (bf16 element offsets)
#define WQ_OFF 0        // qkv_w  [576][192]
#define WP_OFF 110592   // proj_w [192][192]
#define W1_OFF 147456   // fc1_w  [768][192]
#define W2_OFF 294912   // fc2_w  [192][768]
#define WS_ELEMS 442368 // * 2 B = 884736 B of d_ws used

// ---- K0: one-shot fp32 -> bf16 weight conversion into workspace ------------
__global__ __launch_bounds__(256) void w_cvt(const float* __restrict__ qw,
                                             const float* __restrict__ pw,
                                             const float* __restrict__ w1,
                                             const float* __restrict__ w2,
                                             bf16* __restrict__ ws) {
    int i = blockIdx.x * 256 + threadIdx.x;
    if (i < 110592)      ws[i] = f2b(qw[i]);
    else if (i < 147456) ws[i] = f2b(pw[i - 110592]);
    else if (i < 294912) ws[i] = f2b(w1[i - 147456]);
    else if (i < WS_ELEMS) ws[i] = f2b(w2[i - 294912]);
}

// ---- K1: per-window fused LN1 + shift + QKV + attention + proj + residual --
__global__ __launch_bounds__(256) void k_win(const float* __restrict__ x,
                                             const float* __restrict__ g,
                                             const float* __restrict__ bt,
                                             const bf16* __restrict__ wsb,
                                             const float* __restrict__ qbias,
                                             const float* __restrict__ rpb,
                                             const float* __restrict__ pbias,
                                             float* __restrict__ o1) {
    // LDS carve-up (120088 B total, 1 block/CU):
    //  [0      ) Qs  [64][192] swz (Q pre-scaled by 1/sqrt(32))
    //  [24576  ) Ks  [64][192] swz
    //  [49152  ) Vt  [6][32][64] swz rows=d  (V stored transposed)
    //  [73728  ) Pb  [4 waves][32][64] swz   (P transpose buffer, wave-local)
    //  [90112  ) AO  [64][192] swz           (attention output)
    //  [114688 ) rpbs 1350 f32
    //  A (LN1 tile, [64][192] swz) aliases Pb+AO head (dead after phase 2)
    __shared__ __align__(16) char SM[120096];
    bf16* Qs = (bf16*)(SM);
    bf16* Ks = (bf16*)(SM + 24576);
    bf16* Vt = (bf16*)(SM + 49152);
    bf16* Pb = (bf16*)(SM + 73728);
    bf16* AO = (bf16*)(SM + 90112);
    float* rpbs = (float*)(SM + 114688);
    bf16* A = (bf16*)(SM + 73728);   // alias

    int wid = blockIdx.x;
    int bz = wid >> 8, widx = wid & 255;
    int wh = widx >> 4, ww = widx & 15;
    int tid = threadIdx.x, wave = tid >> 6, lane = tid & 63;
    int l15 = lane & 15, l4 = lane >> 4;
    const float SC = 0.1767766952966369f;  // 1/sqrt(32)

    // --- Phase 1: LN1 + cyclic shift -> A ; stage rpb table ---
    {
        float g0 = g[lane], g1 = g[lane + 64], g2 = g[lane + 128];
        float c0 = bt[lane], c1 = bt[lane + 64], c2 = bt[lane + 128];
        for (int t = wave; t < 64; t += 4) {
            int i = t >> 3, j = t & 7;
            int shr = (wh * 8 + i + 4) & 127;   // roll(-4)
            int shc = (ww * 8 + j + 4) & 127;
            const float* px = x + ((size_t)bz * 16384 + shr * 128 + shc) * 192;
            float v0 = px[lane], v1 = px[lane + 64], v2 = px[lane + 128];
            float s = v0 + v1 + v2, ss = v0 * v0 + v1 * v1 + v2 * v2;
#pragma unroll
            for (int o = 32; o > 0; o >>= 1) { s += __shfl_xor(s, o); ss += __shfl_xor(ss, o); }
            float mu = s * (1.f / 192.f);
            float var = fmaxf(ss * (1.f / 192.f) - mu * mu, 0.f);
            float rs = rsqrtf(var + 1e-5f);
            A[sw(t, lane, 192)]       = f2b((v0 - mu) * rs * g0 + c0);
            A[sw(t, lane + 64, 192)]  = f2b((v1 - mu) * rs * g1 + c1);
            A[sw(t, lane + 128, 192)] = f2b((v2 - mu) * rs * g2 + c2);
        }
        for (int i2 = tid; i2 < 1350; i2 += 256) rpbs[i2] = rpb[i2];
    }
    __syncthreads();

    // --- Phase 2: QKV GEMM  (M=64 tok, N=576, K=192). wave covers 144 cols --
    {
        const bf16* Wq = wsb + WQ_OFF;
        int kk0 = l4 << 3;
#pragma unroll 1
        for (int outer = 0; outer < 3; ++outer) {
            int c0 = wave * 144 + outer * 48;
            f32x4 acc[4][3];
#pragma unroll
            for (int m = 0; m < 4; ++m)
#pragma unroll
            for (int n = 0; n < 3; ++n) acc[m][n] = (f32x4){0.f, 0.f, 0.f, 0.f};
#pragma unroll
            for (int ks = 0; ks < 6; ++ks) {
                int kk = ks * 32 + kk0;
                bf16x8 a[4], bb[3];
#pragma unroll
                for (int m = 0; m < 4; ++m)
                    a[m] = *(const bf16x8*)&A[sw(m * 16 + l15, kk, 192)];
#pragma unroll
                for (int n = 0; n < 3; ++n)
                    bb[n] = *(const bf16x8*)&Wq[(c0 + n * 16 + l15) * 192 + kk];
#pragma unroll
                for (int m = 0; m < 4; ++m)
#pragma unroll
                for (int n = 0; n < 3; ++n)
                    acc[m][n] = __builtin_amdgcn_mfma_f32_16x16x32_bf16(a[m], bb[n], acc[m][n], 0, 0, 0);
            }
#pragma unroll
            for (int n = 0; n < 3; ++n) {
                int col = c0 + n * 16 + l15;
                int which = col / 192, cc = col % 192;
                int head = cc >> 5, d = cc & 31;
                float qb = qbias[col];
#pragma unroll
                for (int m = 0; m < 4; ++m)
#pragma unroll
                for (int r = 0; r < 4; ++r) {
                    int tok = m * 16 + (l4 << 2) + r;
                    float v = acc[m][n][r] + qb;
                    if (which == 0)      Qs[sw(tok, cc, 192)] = f2b(v * SC);
                    else if (which == 1) Ks[sw(tok, cc, 192)] = f2b(v);
                    else                 Vt[head * 2048 + sw(d, tok, 64)] = f2b(v);
                }
            }
        }
    }
    __syncthreads();

    // --- Phase 3: attention. 12 units = (head, m-half of 32 q-rows) ---------
    {
        bf16* Pw = Pb + wave * 2048;   // wave-private P transpose buffer
        int kk0 = l4 << 3;
#pragma unroll 1
        for (int ui = 0; ui < 3; ++ui) {
            int u = wave + ui * 4;
            int h = u >> 1, mh = u & 1;
            // QK^T: S[32 q][64 key], K=32
            f32x4 S[2][4];
#pragma unroll
            for (int m = 0; m < 2; ++m)
#pragma unroll
            for (int n = 0; n < 4; ++n) S[m][n] = (f32x4){0.f, 0.f, 0.f, 0.f};
            {
                bf16x8 qa[2], kb[4];
#pragma unroll
                for (int m = 0; m < 2; ++m)
                    qa[m] = *(const bf16x8*)&Qs[sw(mh * 32 + m * 16 + l15, h * 32 + kk0, 192)];
#pragma unroll
                for (int n = 0; n < 4; ++n)
                    kb[n] = *(const bf16x8*)&Ks[sw(n * 16 + l15, h * 32 + kk0, 192)];
#pragma unroll
                for (int m = 0; m < 2; ++m)
#pragma unroll
                for (int n = 0; n < 4; ++n)
                    S[m][n] = __builtin_amdgcn_mfma_f32_16x16x32_bf16(qa[m], kb[n], S[m][n], 0, 0, 0);
            }
            // bias + mask + row softmax on the D-fragment layout
            float inv[2][4];
#pragma unroll
            for (int m = 0; m < 2; ++m)
#pragma unroll
            for (int r = 0; r < 4; ++r) {
                int q = mh * 32 + m * 16 + (l4 << 2) + r;
                int yi = q >> 3, xi = q & 7;
                int li = lab3(wh * 8 + yi) * 3 + lab3(ww * 8 + xi);
                float vv[4];
                float best = -1e30f;
#pragma unroll
                for (int n = 0; n < 4; ++n) {
                    int key = n * 16 + l15;
                    int yj = key >> 3, xj = key & 7;
                    int lj = lab3(wh * 8 + yj) * 3 + lab3(ww * 8 + xj);
                    float v = S[m][n][r] + rpbs[((yi - yj + 7) * 15 + (xi - xj + 7)) * 6 + h];
                    if (li != lj) v -= 100.f;
                    vv[n] = v;
                    best = fmaxf(best, v);
                }
#pragma unroll
                for (int o = 1; o < 16; o <<= 1) best = fmaxf(best, __shfl_xor(best, o));
                float ssum = 0.f;
#pragma unroll
                for (int n = 0; n < 4; ++n) { vv[n] = __expf(vv[n] - best); ssum += vv[n]; }
#pragma unroll
                for (int o = 1; o < 16; o <<= 1) ssum += __shfl_xor(ssum, o);
                inv[m][r] = 1.f / ssum;   // applied at PV epilogue (same lanes hold same q)
                int qloc = m * 16 + (l4 << 2) + r;
#pragma unroll
                for (int n = 0; n < 4; ++n)
                    Pw[sw(qloc, n * 16 + l15, 64)] = f2b(vv[n]);   // unnormalized P
            }
            // wave-local LDS transpose: DS pipe is in-order per wave; fence compiler
            asm volatile("s_waitcnt lgkmcnt(0)" ::: "memory");
            // PV: out[32 q][32 d] = P[32][64] x V[64][32], K split in 2
            f32x4 O[2][2];
#pragma unroll
            for (int m = 0; m < 2; ++m)
#pragma unroll
            for (int n = 0; n < 2; ++n) O[m][n] = (f32x4){0.f, 0.f, 0.f, 0.f};
#pragma unroll
            for (int ksub = 0; ksub < 2; ++ksub) {
                int kk = ksub * 32 + kk0;
                bf16x8 pa[2], vb[2];
#pragma unroll
                for (int m = 0; m < 2; ++m)
                    pa[m] = *(const bf16x8*)&Pw[sw(m * 16 + l15, kk, 64)];
#pragma unroll
                for (int n = 0; n < 2; ++n)
                    vb[n] = *(const bf16x8*)&Vt[h * 2048 + sw(n * 16 + l15, kk, 64)];
#pragma unroll
                for (int m = 0; m < 2; ++m)
#pragma unroll
                for (int n = 0; n < 2; ++n)
                    O[m][n] = __builtin_amdgcn_mfma_f32_16x16x32_bf16(pa[m], vb[n], O[m][n], 0, 0, 0);
            }
#pragma unroll
            for (int m = 0; m < 2; ++m)
#pragma unroll
            for (int n = 0; n < 2; ++n)
#pragma unroll
            for (int r = 0; r < 4; ++r) {
                int q = mh * 32 + m * 16 + (l4 << 2) + r;
                int d = n * 16 + l15;
                AO[sw(q, h * 32 + d, 192)] = f2b(O[m][n][r] * inv[m][r]);
            }
        }
    }
    __syncthreads();

    // --- Phase 4: proj GEMM + window reverse + un-shift + residual ----------
    {
        const bf16* Wp = wsb + WP_OFF;
        int kk0 = l4 << 3;
        int c0 = wave * 48;
        f32x4 acc[4][3];
#pragma unroll
        for (int m = 0; m < 4; ++m)
#pragma unroll
        for (int n = 0; n < 3; ++n) acc[m][n] = (f32x4){0.f, 0.f, 0.f, 0.f};
#pragma unroll
        for (int ks = 0; ks < 6; ++ks) {
            int kk = ks * 32 + kk0;
            bf16x8 a[4], bb[3];
#pragma unroll
            for (int m = 0; m < 4; ++m)
                a[m] = *(const bf16x8*)&AO[sw(m * 16 + l15, kk, 192)];
#pragma unroll
            for (int n = 0; n < 3; ++n)
                bb[n] = *(const bf16x8*)&Wp[(c0 + n * 16 + l15) * 192 + kk];
#pragma unroll
            for (int m = 0; m < 4; ++m)
#pragma unroll
            for (int n = 0; n < 3; ++n)
                acc[m][n] = __builtin_amdgcn_mfma_f32_16x16x32_bf16(a[m], bb[n], acc[m][n], 0, 0, 0);
        }
#pragma unroll
        for (int n = 0; n < 3; ++n) {
            int col = c0 + n * 16 + l15;
            float pb = pbias[col];
#pragma unroll
            for (int m = 0; m < 4; ++m)
#pragma unroll
            for (int r = 0; r < 4; ++r) {
                int tok = m * 16 + (l4 << 2) + r;
                int i = tok >> 3, j = tok & 7;
                int dh = (wh * 8 + i + 4) & 127;   // roll(+4)
                int dw = (ww * 8 + j + 4) & 127;
                size_t dst = ((size_t)bz * 16384 + dh * 128 + dw) * 192 + col;
                o1[dst] = acc[m][n][r] + pb + x[dst];
            }
        }
    }
}

// ---- K2: LN2 + MLP (fc1 + leaky + fc2 + residual), MFMA, in-place on d_out -
__global__ __launch_bounds__(256) void s_mlp(float* __restrict__ o1,
                                             const float* __restrict__ g2,
                                             const float* __restrict__ bt2,
                                             const bf16* __restrict__ wsb,
                                             const float* __restrict__ b1,
                                             const float* __restrict__ b2) {
    __shared__ __align__(16) bf16 As[64 * 192];   // LN2 tile, swz (24.6 KB)
    __shared__ __align__(16) bf16 Hs[64 * 768];   // leaky(fc1) tile, swz (98.3 KB)
    int tid = threadIdx.x, wave = tid >> 6, lane = tid & 63;
    int l15 = lane & 15, l4 = lane >> 4;
    size_t tok0 = (size_t)blockIdx.x * 64;

    {   // LN2 (block-local)
        float g0 = g2[lane], g1 = g2[lane + 64], gg = g2[lane + 128];
        float c0 = bt2[lane], c1 = bt2[lane + 64], c2 = bt2[lane + 128];
        for (int t = wave; t < 64; t += 4) {
            const float* px = o1 + (tok0 + t) * 192;
            float v0 = px[lane], v1 = px[lane + 64], v2 = px[lane + 128];
            float s = v0 + v1 + v2, ss = v0 * v0 + v1 * v1 + v2 * v2;
#pragma unroll
            for (int o = 32; o > 0; o >>= 1) { s += __shfl_xor(s, o); ss += __shfl_xor(ss, o); }
            float mu = s * (1.f / 192.f);
            float var = fmaxf(ss * (1.f / 192.f) - mu * mu, 0.f);
            float rs = rsqrtf(var + 1e-5f);
            As[sw(t, lane, 192)]       = f2b((v0 - mu) * rs * g0 + c0);
            As[sw(t, lane + 64, 192)]  = f2b((v1 - mu) * rs * g1 + c1);
            As[sw(t, lane + 128, 192)] = f2b((v2 - mu) * rs * gg + c2);
        }
    }
    __syncthreads();

    // fc1: M=64, N=768 (wave covers 192 cols), K=192; leaky -> Hs
    {
        const bf16* W1 = wsb + W1_OFF;
        int kk0 = l4 << 3;
#pragma unroll 1
        for (int outer = 0; outer < 3; ++outer) {
            int c0 = wave * 192 + outer * 64;
            f32x4 acc[4][4];
#pragma unroll
            for (int m = 0; m < 4; ++m)
#pragma unroll
            for (int n = 0; n < 4; ++n) acc[m][n] = (f32x4){0.f, 0.f, 0.f, 0.f};
#pragma unroll
            for (int ks = 0; ks < 6; ++ks) {
                int kk = ks * 32 + kk0;
                bf16x8 a[4], bb[4];
#pragma unroll
                for (int m = 0; m < 4; ++m)
                    a[m] = *(const bf16x8*)&As[sw(m * 16 + l15, kk, 192)];
#pragma unroll
                for (int n = 0; n < 4; ++n)
                    bb[n] = *(const bf16x8*)&W1[(c0 + n * 16 + l15) * 192 + kk];
#pragma unroll
                for (int m = 0; m < 4; ++m)
#pragma unroll
                for (int n = 0; n < 4; ++n)
                    acc[m][n] = __builtin_amdgcn_mfma_f32_16x16x32_bf16(a[m], bb[n], acc[m][n], 0, 0, 0);
            }
#pragma unroll
            for (int n = 0; n < 4; ++n) {
                int col = c0 + n * 16 + l15;
                float bb1 = b1[col];
#pragma unroll
                for (int m = 0; m < 4; ++m)
#pragma unroll
                for (int r = 0; r < 4; ++r) {
                    int tok = m * 16 + (l4 << 2) + r;
                    float v = acc[m][n][r] + bb1;
                    v = v > 0.f ? v : 0.2f * v;
                    Hs[sw(tok, col, 768)] = f2b(v);
                }
            }
        }
    }
    __syncthreads();

    // fc2: M=64, N=192 (wave covers 48 cols), K=768; + bias + residual
    {
        const bf16* W2 = wsb + W2_OFF;
        int kk0 = l4 << 3;
        int c0 = wave * 48;
        f32x4 acc[4][3];
#pragma unroll
        for (int m = 0; m < 4; ++m)
#pragma unroll
        for (int n = 0; n < 3; ++n) acc[m][n] = (f32x4){0.f, 0.f, 0.f, 0.f};
        for (int ks = 0; ks < 24; ++ks) {
            int kk = ks * 32 + kk0;
            bf16x8 a[4], bb[3];
#pragma unroll
            for (int m = 0; m < 4; ++m)
                a[m] = *(const bf16x8*)&Hs[sw(m * 16 + l15, kk, 768)];
#pragma unroll
            for (int n = 0; n < 3; ++n)
                bb[n] = *(const bf16x8*)&W2[(c0 + n * 16 + l15) * 768 + kk];
#pragma unroll
            for (int m = 0; m < 4; ++m)
#pragma unroll
            for (int n = 0; n < 3; ++n)
                acc[m][n] = __builtin_amdgcn_mfma_f32_16x16x32_bf16(a[m], bb[n], acc[m][n], 0, 0, 0);
        }
#pragma unroll
        for (int n = 0; n < 3; ++n) {
            int col = c0 + n * 16 + l15;
            float bb2 = b2[col];
#pragma unroll
            for (int m = 0; m < 4; ++m)
#pragma unroll
            for (int r = 0; r < 4; ++r) {
                int tok = m * 16 + (l4 << 2) + r;
                size_t idx = (tok0 + tok) * 192 + col;
                o1[idx] = acc[m][n][r] + bb2 + o1[idx];
            }
        }
    }
}

// ---------------- launch ----------------------------------------------------
extern "C" void kernel_launch(void* const* d_in, const int* in_sizes, int n_in,
                              void* d_out, int out_size, void* d_ws, size_t ws_size,
                              hipStream_t stream) {
    const float* x     = (const float*)d_in[0];
    const float* n1g   = (const float*)d_in[1];
    const float* n1b   = (const float*)d_in[2];
    const float* qkvw  = (const float*)d_in[3];
    const float* qkvb  = (const float*)d_in[4];
    const float* projw = (const float*)d_in[5];
    const float* projb = (const float*)d_in[6];
    const float* rpb   = (const float*)d_in[7];
    const float* n2g   = (const float*)d_in[8];
    const float* n2b   = (const float*)d_in[9];
    const float* fc1w  = (const float*)d_in[10];
    const float* fc1b  = (const float*)d_in[11];
    const float* fc2w  = (const float*)d_in[12];
    const float* fc2b  = (const float*)d_in[13];

    float* o1 = (float*)d_out;         // residual stream lives in d_out
    bf16* wsb = (bf16*)d_ws;           // 884736 B of bf16 weights
    (void)ws_size;

    w_cvt<<<1728, 256, 0, stream>>>(qkvw, projw, fc1w, fc2w, wsb);
    k_win<<<2048, 256, 0, stream>>>(x, n1g, n1b, wsb, qkvb, rpb, projb, o1);
    s_mlp<<<2048, 256, 0, stream>>>(o1, n2g, n2b, wsb, fc1b, fc2b);
}

// Round 2
// 688.179 us; speedup vs baseline: 36.0275x; 1.0998x over previous
//
#include <hip/hip_runtime.h>
#include <hip/hip_bf16.h>

// Swin block: B=8, H=W=128, C=192, NH=6, HD=32, WS=8, SHIFT=4, N=64, NW=256
// ROUND 8: occupancy attack. k_win: 512 thr (2 waves/SIMD). s_mlp: chunked-K
// MLP, 56KB LDS -> 2 blocks/CU (4 waves/SIMD). Weights stored in MFMA
// fragment order so every B-frag load is one coalesced 1KB wave read.

typedef __hip_bfloat16 bf16;
typedef short bf16x8 __attribute__((ext_vector_type(8)));   // 8 bf16 = 4 VGPRs
typedef float f32x4 __attribute__((ext_vector_type(4)));

__device__ __forceinline__ bf16 f2b(float f) { return __float2bfloat16(f); }
__device__ __forceinline__ int lab3(int v) {   // region label along one axis
    return v < 120 ? 0 : (v < 124 ? 1 : 2);    // slices (0,-8),(-8,-4),(-4,None)
}
// swizzled LDS element offset: XOR row low bits into the 16B-block index.
__device__ __forceinline__ int sw(int row, int col, int stride) {
    return row * stride + (col ^ ((row & 7) << 3));
}

// workspace layout (bf16 element offsets) - fragment-ordered weights:
// element ((cb*KS + ks)*64 + lane)*8 + j  ==  W[cb*16 + (lane&15)][ks*32 + (lane>>4)*8 + j]
#define WQ_OFF 0        // qkv_w  [576][192]  cb=36 KS=6
#define WP_OFF 110592   // proj_w [192][192]  cb=12 KS=6
#define W1_OFF 147456   // fc1_w  [768][192]  cb=48 KS=6
#define W2_OFF 294912   // fc2_w  [192][768]  cb=12 KS=24
#define WS_ELEMS 442368

// ---- K0: one-shot fp32 -> bf16 fragment-order weight conversion ------------
__global__ __launch_bounds__(256) void w_cvt(const float* __restrict__ qw,
                                             const float* __restrict__ pw,
                                             const float* __restrict__ w1,
                                             const float* __restrict__ w2,
                                             bf16* __restrict__ ws) {
    int t = blockIdx.x * 256 + threadIdx.x;   // one 8-elem group per thread
    if (t >= 55296) return;                   // 442368/8
    const float* src; int K; int base; int g;
    if (t < 13824)      { src = qw; K = 192; base = WQ_OFF; g = t; }
    else if (t < 18432) { src = pw; K = 192; base = WP_OFF; g = t - 13824; }
    else if (t < 36864) { src = w1; K = 192; base = W1_OFF; g = t - 18432; }
    else                { src = w2; K = 768; base = W2_OFF; g = t - 36864; }
    int KS = K >> 5;
    int cb   = g / (KS * 64);
    int rem  = g % (KS * 64);
    int ks   = rem >> 6;
    int lane = rem & 63;
    int row  = cb * 16 + (lane & 15);
    int k0   = ks * 32 + (lane >> 4) * 8;
    bf16* dst = ws + base + (size_t)g * 8;
    const float* s = src + (size_t)row * K + k0;
#pragma unroll
    for (int j = 0; j < 8; ++j) dst[j] = f2b(s[j]);
}

// ---- K1: per-window fused LN1 + shift + QKV + attention + proj + residual --
__global__ __launch_bounds__(512, 2) void k_win(const float* __restrict__ x,
                                                const float* __restrict__ g,
                                                const float* __restrict__ bt,
                                                const bf16* __restrict__ wsb,
                                                const float* __restrict__ qbias,
                                                const float* __restrict__ rpb,
                                                const float* __restrict__ pbias,
                                                float* __restrict__ o1) {
    // LDS (120088 B): Qs | Ks | Vt | A==AO | Pb(8x2KB) | rpbs
    __shared__ __align__(16) char SM[120096];
    bf16* Qs = (bf16*)(SM);
    bf16* Ks = (bf16*)(SM + 24576);
    bf16* Vt = (bf16*)(SM + 49152);
    bf16* AO = (bf16*)(SM + 73728);
    bf16* Pb = (bf16*)(SM + 98304);
    float* rpbs = (float*)(SM + 114688);
    bf16* A = (bf16*)(SM + 73728);   // alias: LN tile dead before AO written

    int wid = blockIdx.x;
    int bz = wid >> 8, widx = wid & 255;
    int wh = widx >> 4, ww = widx & 15;
    int tid = threadIdx.x, wave = tid >> 6, lane = tid & 63;
    int l15 = lane & 15, l4 = lane >> 4;
    const float SC = 0.1767766952966369f;  // 1/sqrt(32)

    // --- Phase 1: LN1 + cyclic shift -> A ; stage rpb table ---
    {
        float g0 = g[lane], g1 = g[lane + 64], g2 = g[lane + 128];
        float c0 = bt[lane], c1 = bt[lane + 64], c2 = bt[lane + 128];
        for (int t = wave; t < 64; t += 8) {
            int i = t >> 3, j = t & 7;
            int shr = (wh * 8 + i + 4) & 127;   // roll(-4)
            int shc = (ww * 8 + j + 4) & 127;
            const float* px = x + ((size_t)bz * 16384 + shr * 128 + shc) * 192;
            float v0 = px[lane], v1 = px[lane + 64], v2 = px[lane + 128];
            float s = v0 + v1 + v2, ss = v0 * v0 + v1 * v1 + v2 * v2;
#pragma unroll
            for (int o = 32; o > 0; o >>= 1) { s += __shfl_xor(s, o); ss += __shfl_xor(ss, o); }
            float mu = s * (1.f / 192.f);
            float var = fmaxf(ss * (1.f / 192.f) - mu * mu, 0.f);
            float rs = rsqrtf(var + 1e-5f);
            A[sw(t, lane, 192)]       = f2b((v0 - mu) * rs * g0 + c0);
            A[sw(t, lane + 64, 192)]  = f2b((v1 - mu) * rs * g1 + c1);
            A[sw(t, lane + 128, 192)] = f2b((v2 - mu) * rs * g2 + c2);
        }
        for (int i2 = tid; i2 < 1350; i2 += 512) rpbs[i2] = rpb[i2];
    }
    __syncthreads();

    // --- Phase 2: QKV GEMM (M=64, N=576, K=192). wave=(mh rows, cg cols) ----
    {
        const bf16* Wq = wsb + WQ_OFF;
        int kk0 = l4 << 3;
        int mh = wave & 1, cg = wave >> 1;     // rows mh*32, cols cg*144
#pragma unroll 1
        for (int outer = 0; outer < 3; ++outer) {
            int c0 = cg * 144 + outer * 48;
            int cb0 = c0 >> 4;
            f32x4 acc[2][3];
#pragma unroll
            for (int m = 0; m < 2; ++m)
#pragma unroll
            for (int n = 0; n < 3; ++n) acc[m][n] = (f32x4){0.f, 0.f, 0.f, 0.f};
#pragma unroll
            for (int ks = 0; ks < 6; ++ks) {
                int kk = ks * 32 + kk0;
                bf16x8 a[2], bb[3];
#pragma unroll
                for (int m = 0; m < 2; ++m)
                    a[m] = *(const bf16x8*)&A[sw(mh * 32 + m * 16 + l15, kk, 192)];
#pragma unroll
                for (int n = 0; n < 3; ++n)
                    bb[n] = *(const bf16x8*)&Wq[((cb0 + n) * 6 + ks) * 512 + (lane << 3)];
#pragma unroll
                for (int m = 0; m < 2; ++m)
#pragma unroll
                for (int n = 0; n < 3; ++n)
                    acc[m][n] = __builtin_amdgcn_mfma_f32_16x16x32_bf16(a[m], bb[n], acc[m][n], 0, 0, 0);
            }
#pragma unroll
            for (int n = 0; n < 3; ++n) {
                int col = c0 + n * 16 + l15;
                int which = col / 192, cc = col % 192;
                int head = cc >> 5, d = cc & 31;
                float qb = qbias[col];
#pragma unroll
                for (int m = 0; m < 2; ++m)
#pragma unroll
                for (int r = 0; r < 4; ++r) {
                    int tok = mh * 32 + m * 16 + (l4 << 2) + r;
                    float v = acc[m][n][r] + qb;
                    if (which == 0)      Qs[sw(tok, cc, 192)] = f2b(v * SC);
                    else if (which == 1) Ks[sw(tok, cc, 192)] = f2b(v);
                    else                 Vt[head * 2048 + sw(d, tok, 64)] = f2b(v);
                }
            }
        }
    }
    __syncthreads();

    // --- Phase 3: attention. 24 units = (head, 16-row quarter), 3 per wave --
    {
        bf16* Pw = Pb + wave * 1024;   // wave-private [16][64] swz
        int kk0 = l4 << 3;
#pragma unroll 1
        for (int ui = 0; ui < 3; ++ui) {
            int u = wave + ui * 8;
            int h = u >> 2, mq = u & 3;
            // QK^T: S[16 q][64 key], K=32
            f32x4 S[4];
            bf16x8 qa = *(const bf16x8*)&Qs[sw(mq * 16 + l15, h * 32 + kk0, 192)];
#pragma unroll
            for (int n = 0; n < 4; ++n) {
                bf16x8 kb = *(const bf16x8*)&Ks[sw(n * 16 + l15, h * 32 + kk0, 192)];
                S[n] = __builtin_amdgcn_mfma_f32_16x16x32_bf16(qa, kb, (f32x4){0.f,0.f,0.f,0.f}, 0, 0, 0);
            }
            // bias + mask + row softmax on D-fragment layout
            float inv[4];
#pragma unroll
            for (int r = 0; r < 4; ++r) {
                int q = mq * 16 + (l4 << 2) + r;
                int yi = q >> 3, xi = q & 7;
                int li = lab3(wh * 8 + yi) * 3 + lab3(ww * 8 + xi);
                float vv[4];
                float best = -1e30f;
#pragma unroll
                for (int n = 0; n < 4; ++n) {
                    int key = n * 16 + l15;
                    int yj = key >> 3, xj = key & 7;
                    int lj = lab3(wh * 8 + yj) * 3 + lab3(ww * 8 + xj);
                    float v = S[n][r] + rpbs[((yi - yj + 7) * 15 + (xi - xj + 7)) * 6 + h];
                    if (li != lj) v -= 100.f;
                    vv[n] = v;
                    best = fmaxf(best, v);
                }
#pragma unroll
                for (int o = 1; o < 16; o <<= 1) best = fmaxf(best, __shfl_xor(best, o));
                float ssum = 0.f;
#pragma unroll
                for (int n = 0; n < 4; ++n) { vv[n] = __expf(vv[n] - best); ssum += vv[n]; }
#pragma unroll
                for (int o = 1; o < 16; o <<= 1) ssum += __shfl_xor(ssum, o);
                inv[r] = 1.f / ssum;
                int qloc = (l4 << 2) + r;
#pragma unroll
                for (int n = 0; n < 4; ++n)
                    Pw[sw(qloc, n * 16 + l15, 64)] = f2b(vv[n]);   // unnormalized P
            }
            // wave-local LDS transpose: DS pipe in-order per wave
            asm volatile("s_waitcnt lgkmcnt(0)" ::: "memory");
            // PV: out[16 q][32 d] = P[16][64] x V[64][32]
            f32x4 O[2];
#pragma unroll
            for (int n = 0; n < 2; ++n) O[n] = (f32x4){0.f, 0.f, 0.f, 0.f};
#pragma unroll
            for (int ksub = 0; ksub < 2; ++ksub) {
                int kk = ksub * 32 + kk0;
                bf16x8 pa = *(const bf16x8*)&Pw[sw(l15, kk, 64)];
#pragma unroll
                for (int n = 0; n < 2; ++n) {
                    bf16x8 vb = *(const bf16x8*)&Vt[h * 2048 + sw(n * 16 + l15, kk, 64)];
                    O[n] = __builtin_amdgcn_mfma_f32_16x16x32_bf16(pa, vb, O[n], 0, 0, 0);
                }
            }
#pragma unroll
            for (int n = 0; n < 2; ++n)
#pragma unroll
            for (int r = 0; r < 4; ++r) {
                int q = mq * 16 + (l4 << 2) + r;
                int d = n * 16 + l15;
                AO[sw(q, h * 32 + d, 192)] = f2b(O[n][r] * inv[r]);
            }
        }
    }
    __syncthreads();

    // --- Phase 4: proj GEMM + window reverse + un-shift + residual ----------
    {
        const bf16* Wp = wsb + WP_OFF;
        int kk0 = l4 << 3;
        int mh = wave & 1, cg = wave >> 1;     // rows mh*32, cols cg*48
        int c0 = cg * 48, cb0 = c0 >> 4;
        f32x4 acc[2][3];
#pragma unroll
        for (int m = 0; m < 2; ++m)
#pragma unroll
        for (int n = 0; n < 3; ++n) acc[m][n] = (f32x4){0.f, 0.f, 0.f, 0.f};
#pragma unroll
        for (int ks = 0; ks < 6; ++ks) {
            int kk = ks * 32 + kk0;
            bf16x8 a[2], bb[3];
#pragma unroll
            for (int m = 0; m < 2; ++m)
                a[m] = *(const bf16x8*)&AO[sw(mh * 32 + m * 16 + l15, kk, 192)];
#pragma unroll
            for (int n = 0; n < 3; ++n)
                bb[n] = *(const bf16x8*)&Wp[((cb0 + n) * 6 + ks) * 512 + (lane << 3)];
#pragma unroll
            for (int m = 0; m < 2; ++m)
#pragma unroll
            for (int n = 0; n < 3; ++n)
                acc[m][n] = __builtin_amdgcn_mfma_f32_16x16x32_bf16(a[m], bb[n], acc[m][n], 0, 0, 0);
        }
#pragma unroll
        for (int n = 0; n < 3; ++n) {
            int col = c0 + n * 16 + l15;
            float pb = pbias[col];
#pragma unroll
            for (int m = 0; m < 2; ++m)
#pragma unroll
            for (int r = 0; r < 4; ++r) {
                int tok = mh * 32 + m * 16 + (l4 << 2) + r;
                int i = tok >> 3, j = tok & 7;
                int dh = (wh * 8 + i + 4) & 127;   // roll(+4)
                int dw = (ww * 8 + j + 4) & 127;
                size_t dst = ((size_t)bz * 16384 + dh * 128 + dw) * 192 + col;
                o1[dst] = acc[m][n][r] + pb + x[dst];
            }
        }
    }
}

// ---- K2: LN2 + MLP, chunked-K (56KB LDS -> 2 blocks/CU), in-place on d_out -
__global__ __launch_bounds__(512, 4) void s_mlp(float* __restrict__ o1,
                                                const float* __restrict__ g2,
                                                const float* __restrict__ bt2,
                                                const bf16* __restrict__ wsb,
                                                const float* __restrict__ b1,
                                                const float* __restrict__ b2) {
    __shared__ __align__(16) bf16 As[64 * 192];   // LN2 tile, swz (24.6 KB)
    __shared__ __align__(16) bf16 Hs[64 * 256];   // fc1 chunk tile, swz (32.8 KB)
    int tid = threadIdx.x, wave = tid >> 6, lane = tid & 63;
    int l15 = lane & 15, l4 = lane >> 4;
    int kk0 = l4 << 3;
    int mh = wave & 1, cg = wave >> 1;
    size_t tok0 = (size_t)blockIdx.x * 64;

    {   // LN2 (block-local)
        float g0 = g2[lane], g1 = g2[lane + 64], gg = g2[lane + 128];
        float c0 = bt2[lane], c1 = bt2[lane + 64], c2 = bt2[lane + 128];
        for (int t = wave; t < 64; t += 8) {
            const float* px = o1 + (tok0 + t) * 192;
            float v0 = px[lane], v1 = px[lane + 64], v2 = px[lane + 128];
            float s = v0 + v1 + v2, ss = v0 * v0 + v1 * v1 + v2 * v2;
#pragma unroll
            for (int o = 32; o > 0; o >>= 1) { s += __shfl_xor(s, o); ss += __shfl_xor(ss, o); }
            float mu = s * (1.f / 192.f);
            float var = fmaxf(ss * (1.f / 192.f) - mu * mu, 0.f);
            float rs = rsqrtf(var + 1e-5f);
            As[sw(t, lane, 192)]       = f2b((v0 - mu) * rs * g0 + c0);
            As[sw(t, lane + 64, 192)]  = f2b((v1 - mu) * rs * g1 + c1);
            As[sw(t, lane + 128, 192)] = f2b((v2 - mu) * rs * gg + c2);
        }
    }
    __syncthreads();

    // persistent fc2 partial acc: rows mh*32, cols cg*48
    f32x4 acc2[2][3];
#pragma unroll
    for (int m = 0; m < 2; ++m)
#pragma unroll
    for (int n = 0; n < 3; ++n) acc2[m][n] = (f32x4){0.f, 0.f, 0.f, 0.f};

    const bf16* W1 = wsb + W1_OFF;
    const bf16* W2 = wsb + W2_OFF;
#pragma unroll 1
    for (int c = 0; c < 3; ++c) {           // 3 chunks of 256 fc1 cols
        // fc1 chunk: rows mh*32 (2 frags), cols cg*64 within chunk (4 frags)
        {
            f32x4 acc1[2][4];
#pragma unroll
            for (int m = 0; m < 2; ++m)
#pragma unroll
            for (int n = 0; n < 4; ++n) acc1[m][n] = (f32x4){0.f, 0.f, 0.f, 0.f};
            int cb0 = c * 16 + cg * 4;      // W1 col-block base
#pragma unroll
            for (int ks = 0; ks < 6; ++ks) {
                int kk = ks * 32 + kk0;
                bf16x8 a[2], bb[4];
#pragma unroll
                for (int m = 0; m < 2; ++m)
                    a[m] = *(const bf16x8*)&As[sw(mh * 32 + m * 16 + l15, kk, 192)];
#pragma unroll
                for (int n = 0; n < 4; ++n)
                    bb[n] = *(const bf16x8*)&W1[((cb0 + n) * 6 + ks) * 512 + (lane << 3)];
#pragma unroll
                for (int m = 0; m < 2; ++m)
#pragma unroll
                for (int n = 0; n < 4; ++n)
                    acc1[m][n] = __builtin_amdgcn_mfma_f32_16x16x32_bf16(a[m], bb[n], acc1[m][n], 0, 0, 0);
            }
#pragma unroll
            for (int n = 0; n < 4; ++n) {
                int colc = cg * 64 + n * 16 + l15;          // col within chunk
                float bb1 = b1[c * 256 + colc];
#pragma unroll
                for (int m = 0; m < 2; ++m)
#pragma unroll
                for (int r = 0; r < 4; ++r) {
                    int tok = mh * 32 + m * 16 + (l4 << 2) + r;
                    float v = acc1[m][n][r] + bb1;
                    v = v > 0.f ? v : 0.2f * v;
                    Hs[sw(tok, colc, 256)] = f2b(v);
                }
            }
        }
        __syncthreads();
        // fc2 partial: K += 256 from Hs
        {
#pragma unroll
            for (int ks = 0; ks < 8; ++ks) {
                int kk = ks * 32 + kk0;
                bf16x8 a[2], bb[3];
#pragma unroll
                for (int m = 0; m < 2; ++m)
                    a[m] = *(const bf16x8*)&Hs[sw(mh * 32 + m * 16 + l15, kk, 256)];
#pragma unroll
                for (int n = 0; n < 3; ++n)
                    bb[n] = *(const bf16x8*)&W2[((cg * 3 + n) * 24 + c * 8 + ks) * 512 + (lane << 3)];
#pragma unroll
                for (int m = 0; m < 2; ++m)
#pragma unroll
                for (int n = 0; n < 3; ++n)
                    acc2[m][n] = __builtin_amdgcn_mfma_f32_16x16x32_bf16(a[m], bb[n], acc2[m][n], 0, 0, 0);
            }
        }
        __syncthreads();   // before next fc1 overwrites Hs
    }

    // epilogue: bias + residual, in-place
#pragma unroll
    for (int n = 0; n < 3; ++n) {
        int col = cg * 48 + n * 16 + l15;
        float bb2 = b2[col];
#pragma unroll
        for (int m = 0; m < 2; ++m)
#pragma unroll
        for (int r = 0; r < 4; ++r) {
            int tok = mh * 32 + m * 16 + (l4 << 2) + r;
            size_t idx = (tok0 + tok) * 192 + col;
            o1[idx] = acc2[m][n][r] + bb2 + o1[idx];
        }
    }
}

// ---------------- launch ----------------------------------------------------
extern "C" void kernel_launch(void* const* d_in, const int* in_sizes, int n_in,
                              void* d_out, int out_size, void* d_ws, size_t ws_size,
                              hipStream_t stream) {
    const float* x     = (const float*)d_in[0];
    const float* n1g   = (const float*)d_in[1];
    const float* n1b   = (const float*)d_in[2];
    const float* qkvw  = (const float*)d_in[3];
    const float* qkvb  = (const float*)d_in[4];
    const float* projw = (const float*)d_in[5];
    const float* projb = (const float*)d_in[6];
    const float* rpb   = (const float*)d_in[7];
    const float* n2g   = (const float*)d_in[8];
    const float* n2b   = (const float*)d_in[9];
    const float* fc1w  = (const float*)d_in[10];
    const float* fc1b  = (const float*)d_in[11];
    const float* fc2w  = (const float*)d_in[12];
    const float* fc2b  = (const float*)d_in[13];

    float* o1 = (float*)d_out;         // residual stream lives in d_out
    bf16* wsb = (bf16*)d_ws;           // 884736 B of bf16 weights (frag order)
    (void)ws_size; (void)in_sizes; (void)n_in; (void)out_size;

    w_cvt<<<216, 256, 0, stream>>>(qkvw, projw, fc1w, fc2w, wsb);
    k_win<<<2048, 512, 0, stream>>>(x, n1g, n1b, wsb, qkvb, rpb, projb, o1);
    s_mlp<<<2048, 512, 0, stream>>>(o1, n2g, n2b, wsb, fc1b, fc2b);
}

// Round 3
// 520.779 us; speedup vs baseline: 47.6082x; 1.3214x over previous
//
#include <hip/hip_runtime.h>
#include <hip/hip_bf16.h>

// Swin block: B=8, H=W=128, C=192, NH=6, HD=32, WS=8, SHIFT=4, N=64, NW=256
// ROUND 9: latency attack.
//  - k_win: 1024 threads (16 waves = 4/SIMD, 50% occupancy), same LDS plan.
//  - s_mlp: M=128 tokens/block (halves per-token weight re-stream), chunked
//    fc1/fc2 with DOUBLE-BUFFERED Hs (one barrier per chunk), 16 waves.
//  - streaming tensors (x, o1) use non-temporal loads/stores so they stop
//    evicting the 884KB weight set from per-XCD L2 (R8: 190MB of weight
//    re-fetch in FETCH_SIZE).

typedef __hip_bfloat16 bf16;
typedef short bf16x8 __attribute__((ext_vector_type(8)));   // 8 bf16 = 4 VGPRs
typedef float f32x4 __attribute__((ext_vector_type(4)));

__device__ __forceinline__ bf16 f2b(float f) { return __float2bfloat16(f); }
__device__ __forceinline__ int lab3(int v) {   // region label along one axis
    return v < 120 ? 0 : (v < 124 ? 1 : 2);    // slices (0,-8),(-8,-4),(-4,None)
}
// swizzled LDS element offset: XOR row low bits into the 16B-block index.
__device__ __forceinline__ int sw(int row, int col, int stride) {
    return row * stride + (col ^ ((row & 7) << 3));
}
#define NTL(p)    __builtin_nontemporal_load(p)
#define NTS(v, p) __builtin_nontemporal_store(v, p)

// workspace layout (bf16 element offsets) - fragment-ordered weights:
// element ((cb*KS + ks)*64 + lane)*8 + j  ==  W[cb*16 + (lane&15)][ks*32 + (lane>>4)*8 + j]
#define WQ_OFF 0        // qkv_w  [576][192]  cb=36 KS=6
#define WP_OFF 110592   // proj_w [192][192]  cb=12 KS=6
#define W1_OFF 147456   // fc1_w  [768][192]  cb=48 KS=6
#define W2_OFF 294912   // fc2_w  [192][768]  cb=12 KS=24
#define WS_ELEMS 442368

// ---- K0: one-shot fp32 -> bf16 fragment-order weight conversion ------------
__global__ __launch_bounds__(256) void w_cvt(const float* __restrict__ qw,
                                             const float* __restrict__ pw,
                                             const float* __restrict__ w1,
                                             const float* __restrict__ w2,
                                             bf16* __restrict__ ws) {
    int t = blockIdx.x * 256 + threadIdx.x;   // one 8-elem group per thread
    if (t >= 55296) return;                   // 442368/8
    const float* src; int K; int base; int g;
    if (t < 13824)      { src = qw; K = 192; base = WQ_OFF; g = t; }
    else if (t < 18432) { src = pw; K = 192; base = WP_OFF; g = t - 13824; }
    else if (t < 36864) { src = w1; K = 192; base = W1_OFF; g = t - 18432; }
    else                { src = w2; K = 768; base = W2_OFF; g = t - 36864; }
    int KS = K >> 5;
    int cb   = g / (KS * 64);
    int rem  = g % (KS * 64);
    int ks   = rem >> 6;
    int lane = rem & 63;
    int row  = cb * 16 + (lane & 15);
    int k0   = ks * 32 + (lane >> 4) * 8;
    bf16* dst = ws + base + (size_t)g * 8;
    const float* s = src + (size_t)row * K + k0;
#pragma unroll
    for (int j = 0; j < 8; ++j) dst[j] = f2b(s[j]);
}

// ---- K1: per-window fused LN1 + shift + QKV + attention + proj + residual --
__global__ __launch_bounds__(1024, 4) void k_win(const float* __restrict__ x,
                                                 const float* __restrict__ g,
                                                 const float* __restrict__ bt,
                                                 const bf16* __restrict__ wsb,
                                                 const float* __restrict__ qbias,
                                                 const float* __restrict__ rpb,
                                                 const float* __restrict__ pbias,
                                                 float* __restrict__ o1) {
    // LDS (136.5 KB): Qs | Ks | Vt | A==AO | Pb(16x2KB) | rpbs
    __shared__ __align__(16) char SM[136512];
    bf16* Qs = (bf16*)(SM);
    bf16* Ks = (bf16*)(SM + 24576);
    bf16* Vt = (bf16*)(SM + 49152);
    bf16* AO = (bf16*)(SM + 73728);
    bf16* Pb = (bf16*)(SM + 98304);
    float* rpbs = (float*)(SM + 131072);
    bf16* A = (bf16*)(SM + 73728);   // alias: LN tile dead before AO written

    int wid = blockIdx.x;
    int bz = wid >> 8, widx = wid & 255;
    int wh = widx >> 4, ww = widx & 15;
    int tid = threadIdx.x, wave = tid >> 6, lane = tid & 63;
    int l15 = lane & 15, l4 = lane >> 4;
    int kk0 = l4 << 3;
    const float SC = 0.1767766952966369f;  // 1/sqrt(32)

    // --- Phase 1: LN1 + cyclic shift -> A ; stage rpb table ---
    {
        float g0 = g[lane], g1 = g[lane + 64], g2 = g[lane + 128];
        float c0 = bt[lane], c1 = bt[lane + 64], c2 = bt[lane + 128];
        for (int t = wave; t < 64; t += 16) {
            int i = t >> 3, j = t & 7;
            int shr = (wh * 8 + i + 4) & 127;   // roll(-4)
            int shc = (ww * 8 + j + 4) & 127;
            const float* px = x + ((size_t)bz * 16384 + shr * 128 + shc) * 192;
            float v0 = NTL(&px[lane]), v1 = NTL(&px[lane + 64]), v2 = NTL(&px[lane + 128]);
            float s = v0 + v1 + v2, ss = v0 * v0 + v1 * v1 + v2 * v2;
#pragma unroll
            for (int o = 32; o > 0; o >>= 1) { s += __shfl_xor(s, o); ss += __shfl_xor(ss, o); }
            float mu = s * (1.f / 192.f);
            float var = fmaxf(ss * (1.f / 192.f) - mu * mu, 0.f);
            float rs = rsqrtf(var + 1e-5f);
            A[sw(t, lane, 192)]       = f2b((v0 - mu) * rs * g0 + c0);
            A[sw(t, lane + 64, 192)]  = f2b((v1 - mu) * rs * g1 + c1);
            A[sw(t, lane + 128, 192)] = f2b((v2 - mu) * rs * g2 + c2);
        }
        for (int i2 = tid; i2 < 1350; i2 += 1024) rpbs[i2] = rpb[i2];
    }
    __syncthreads();

    // --- Phase 2: QKV GEMM (M=64, N=576, K=192). wave=(mq 16 rows, cg cols) -
    {
        const bf16* Wq = wsb + WQ_OFF;
        int mq = wave & 3, cg = wave >> 2;     // rows mq*16, cols cg*144
#pragma unroll 1
        for (int outer = 0; outer < 3; ++outer) {
            int c0 = cg * 144 + outer * 48;
            int cb0 = cg * 9 + outer * 3;
            f32x4 acc[3];
#pragma unroll
            for (int n = 0; n < 3; ++n) acc[n] = (f32x4){0.f, 0.f, 0.f, 0.f};
#pragma unroll
            for (int ks = 0; ks < 6; ++ks) {
                int kk = ks * 32 + kk0;
                bf16x8 a = *(const bf16x8*)&A[sw(mq * 16 + l15, kk, 192)];
                bf16x8 bb[3];
#pragma unroll
                for (int n = 0; n < 3; ++n)
                    bb[n] = *(const bf16x8*)&Wq[((cb0 + n) * 6 + ks) * 512 + (lane << 3)];
#pragma unroll
                for (int n = 0; n < 3; ++n)
                    acc[n] = __builtin_amdgcn_mfma_f32_16x16x32_bf16(a, bb[n], acc[n], 0, 0, 0);
            }
#pragma unroll
            for (int n = 0; n < 3; ++n) {
                int col = c0 + n * 16 + l15;
                int which = col / 192, cc = col % 192;
                int head = cc >> 5, d = cc & 31;
                float qb = qbias[col];
#pragma unroll
                for (int r = 0; r < 4; ++r) {
                    int tok = mq * 16 + (l4 << 2) + r;
                    float v = acc[n][r] + qb;
                    if (which == 0)      Qs[sw(tok, cc, 192)] = f2b(v * SC);
                    else if (which == 1) Ks[sw(tok, cc, 192)] = f2b(v);
                    else                 Vt[head * 2048 + sw(d, tok, 64)] = f2b(v);
                }
            }
        }
    }
    __syncthreads();

    // --- Phase 3: attention. 24 units = (head, 16-row quarter) over 16 waves
    {
        bf16* Pw = Pb + wave * 1024;   // wave-private [16][64] swz
#pragma unroll 1
        for (int ui = 0; ui < 2; ++ui) {
            int u = wave + ui * 16;
            if (u >= 24) break;
            int h = u >> 2, mq = u & 3;
            // QK^T: S[16 q][64 key], K=32
            f32x4 S[4];
            bf16x8 qa = *(const bf16x8*)&Qs[sw(mq * 16 + l15, h * 32 + kk0, 192)];
#pragma unroll
            for (int n = 0; n < 4; ++n) {
                bf16x8 kb = *(const bf16x8*)&Ks[sw(n * 16 + l15, h * 32 + kk0, 192)];
                S[n] = __builtin_amdgcn_mfma_f32_16x16x32_bf16(qa, kb, (f32x4){0.f,0.f,0.f,0.f}, 0, 0, 0);
            }
            // bias + mask + row softmax on D-fragment layout
            float inv[4];
#pragma unroll
            for (int r = 0; r < 4; ++r) {
                int q = mq * 16 + (l4 << 2) + r;
                int yi = q >> 3, xi = q & 7;
                int li = lab3(wh * 8 + yi) * 3 + lab3(ww * 8 + xi);
                float vv[4];
                float best = -1e30f;
#pragma unroll
                for (int n = 0; n < 4; ++n) {
                    int key = n * 16 + l15;
                    int yj = key >> 3, xj = key & 7;
                    int lj = lab3(wh * 8 + yj) * 3 + lab3(ww * 8 + xj);
                    float v = S[n][r] + rpbs[((yi - yj + 7) * 15 + (xi - xj + 7)) * 6 + h];
                    if (li != lj) v -= 100.f;
                    vv[n] = v;
                    best = fmaxf(best, v);
                }
#pragma unroll
                for (int o = 1; o < 16; o <<= 1) best = fmaxf(best, __shfl_xor(best, o));
                float ssum = 0.f;
#pragma unroll
                for (int n = 0; n < 4; ++n) { vv[n] = __expf(vv[n] - best); ssum += vv[n]; }
#pragma unroll
                for (int o = 1; o < 16; o <<= 1) ssum += __shfl_xor(ssum, o);
                inv[r] = 1.f / ssum;
                int qloc = (l4 << 2) + r;
#pragma unroll
                for (int n = 0; n < 4; ++n)
                    Pw[sw(qloc, n * 16 + l15, 64)] = f2b(vv[n]);   // unnormalized P
            }
            // wave-local LDS transpose: DS pipe in-order per wave
            asm volatile("s_waitcnt lgkmcnt(0)" ::: "memory");
            // PV: out[16 q][32 d] = P[16][64] x V[64][32]
            f32x4 O[2];
#pragma unroll
            for (int n = 0; n < 2; ++n) O[n] = (f32x4){0.f, 0.f, 0.f, 0.f};
#pragma unroll
            for (int ksub = 0; ksub < 2; ++ksub) {
                int kk = ksub * 32 + kk0;
                bf16x8 pa = *(const bf16x8*)&Pw[sw(l15, kk, 64)];
#pragma unroll
                for (int n = 0; n < 2; ++n) {
                    bf16x8 vb = *(const bf16x8*)&Vt[h * 2048 + sw(n * 16 + l15, kk, 64)];
                    O[n] = __builtin_amdgcn_mfma_f32_16x16x32_bf16(pa, vb, O[n], 0, 0, 0);
                }
            }
#pragma unroll
            for (int n = 0; n < 2; ++n)
#pragma unroll
            for (int r = 0; r < 4; ++r) {
                int q = mq * 16 + (l4 << 2) + r;
                int d = n * 16 + l15;
                AO[sw(q, h * 32 + d, 192)] = f2b(O[n][r] * inv[r]);
            }
        }
    }
    __syncthreads();

    // --- Phase 4: proj GEMM + window reverse + un-shift + residual ----------
    {
        const bf16* Wp = wsb + WP_OFF;
        int mq = wave & 3, cg = wave >> 2;     // rows mq*16, cols cg*48
        int c0 = cg * 48, cb0 = cg * 3;
        f32x4 acc[3];
#pragma unroll
        for (int n = 0; n < 3; ++n) acc[n] = (f32x4){0.f, 0.f, 0.f, 0.f};
#pragma unroll
        for (int ks = 0; ks < 6; ++ks) {
            int kk = ks * 32 + kk0;
            bf16x8 a = *(const bf16x8*)&AO[sw(mq * 16 + l15, kk, 192)];
            bf16x8 bb[3];
#pragma unroll
            for (int n = 0; n < 3; ++n)
                bb[n] = *(const bf16x8*)&Wp[((cb0 + n) * 6 + ks) * 512 + (lane << 3)];
#pragma unroll
            for (int n = 0; n < 3; ++n)
                acc[n] = __builtin_amdgcn_mfma_f32_16x16x32_bf16(a, bb[n], acc[n], 0, 0, 0);
        }
#pragma unroll
        for (int n = 0; n < 3; ++n) {
            int col = c0 + n * 16 + l15;
            float pb = pbias[col];
#pragma unroll
            for (int r = 0; r < 4; ++r) {
                int tok = mq * 16 + (l4 << 2) + r;
                int i = tok >> 3, j = tok & 7;
                int dh = (wh * 8 + i + 4) & 127;   // roll(+4)
                int dw = (ww * 8 + j + 4) & 127;
                size_t dst = ((size_t)bz * 16384 + dh * 128 + dw) * 192 + col;
                float xr = NTL(&x[dst]);
                NTS(acc[n][r] + pb + xr, &o1[dst]);
            }
        }
    }
}

// ---- K2: LN2 + MLP. M=128/block, dbuf Hs chunks (1 barrier/chunk), 16 waves
__global__ __launch_bounds__(1024, 4) void s_mlp(float* __restrict__ o1,
                                                 const float* __restrict__ g2,
                                                 const float* __restrict__ bt2,
                                                 const bf16* __restrict__ wsb,
                                                 const float* __restrict__ b1,
                                                 const float* __restrict__ b2) {
    __shared__ __align__(16) bf16 As[128 * 192];     // LN2 tile, swz (49.2 KB)
    __shared__ __align__(16) bf16 Hs[2][128 * 128];  // fc1 chunk dbuf (65.5 KB)
    int tid = threadIdx.x, wave = tid >> 6, lane = tid & 63;
    int l15 = lane & 15, l4 = lane >> 4;
    int kk0 = l4 << 3;
    int mq = wave & 3, cg = wave >> 2;   // rows mq*32; fc2 cols cg*48; fc1 chunk-cols cg*32
    size_t tok0 = (size_t)blockIdx.x * 128;

    {   // LN2 (block-local), nt reads of o1
        float g0 = g2[lane], g1 = g2[lane + 64], gg = g2[lane + 128];
        float c0 = bt2[lane], c1 = bt2[lane + 64], c2 = bt2[lane + 128];
        for (int t = wave; t < 128; t += 16) {
            const float* px = o1 + (tok0 + t) * 192;
            float v0 = NTL(&px[lane]), v1 = NTL(&px[lane + 64]), v2 = NTL(&px[lane + 128]);
            float s = v0 + v1 + v2, ss = v0 * v0 + v1 * v1 + v2 * v2;
#pragma unroll
            for (int o = 32; o > 0; o >>= 1) { s += __shfl_xor(s, o); ss += __shfl_xor(ss, o); }
            float mu = s * (1.f / 192.f);
            float var = fmaxf(ss * (1.f / 192.f) - mu * mu, 0.f);
            float rs = rsqrtf(var + 1e-5f);
            As[sw(t, lane, 192)]       = f2b((v0 - mu) * rs * g0 + c0);
            As[sw(t, lane + 64, 192)]  = f2b((v1 - mu) * rs * g1 + c1);
            As[sw(t, lane + 128, 192)] = f2b((v2 - mu) * rs * gg + c2);
        }
    }
    __syncthreads();

    const bf16* W1 = wsb + W1_OFF;
    const bf16* W2 = wsb + W2_OFF;

    // persistent fc2 partial acc: rows mq*32, cols cg*48
    f32x4 acc2[2][3];
#pragma unroll
    for (int m = 0; m < 2; ++m)
#pragma unroll
    for (int n = 0; n < 3; ++n) acc2[m][n] = (f32x4){0.f, 0.f, 0.f, 0.f};

    // fc1 for chunk c (128 cols) into Hs[buf]; wave covers cols cg*32 (2 frags)
    auto FC1 = [&](int c, int buf) {
        f32x4 acc1[2][2];
#pragma unroll
        for (int m = 0; m < 2; ++m)
#pragma unroll
        for (int n = 0; n < 2; ++n) acc1[m][n] = (f32x4){0.f, 0.f, 0.f, 0.f};
        int cb0 = c * 8 + cg * 2;     // W1 col-block base
#pragma unroll
        for (int ks = 0; ks < 6; ++ks) {
            int kk = ks * 32 + kk0;
            bf16x8 a[2], bb[2];
#pragma unroll
            for (int m = 0; m < 2; ++m)
                a[m] = *(const bf16x8*)&As[sw(mq * 32 + m * 16 + l15, kk, 192)];
#pragma unroll
            for (int n = 0; n < 2; ++n)
                bb[n] = *(const bf16x8*)&W1[((cb0 + n) * 6 + ks) * 512 + (lane << 3)];
#pragma unroll
            for (int m = 0; m < 2; ++m)
#pragma unroll
            for (int n = 0; n < 2; ++n)
                acc1[m][n] = __builtin_amdgcn_mfma_f32_16x16x32_bf16(a[m], bb[n], acc1[m][n], 0, 0, 0);
        }
#pragma unroll
        for (int n = 0; n < 2; ++n) {
            int colc = cg * 32 + n * 16 + l15;          // col within chunk
            float bb1 = b1[c * 128 + colc];
#pragma unroll
            for (int m = 0; m < 2; ++m)
#pragma unroll
            for (int r = 0; r < 4; ++r) {
                int tok = mq * 32 + m * 16 + (l4 << 2) + r;
                float v = acc1[m][n][r] + bb1;
                v = v > 0.f ? v : 0.2f * v;
                Hs[buf][sw(tok, colc, 128)] = f2b(v);
            }
        }
    };

    FC1(0, 0);
    __syncthreads();
#pragma unroll 1
    for (int c = 0; c < 6; ++c) {
        if (c < 5) FC1(c + 1, (c + 1) & 1);   // produce next chunk into other buf
        // fc2 partial from Hs[c&1]: K += 128
#pragma unroll
        for (int ks = 0; ks < 4; ++ks) {
            int kk = ks * 32 + kk0;
            bf16x8 a[2], bb[3];
#pragma unroll
            for (int m = 0; m < 2; ++m)
                a[m] = *(const bf16x8*)&Hs[c & 1][sw(mq * 32 + m * 16 + l15, kk, 128)];
#pragma unroll
            for (int n = 0; n < 3; ++n)
                bb[n] = *(const bf16x8*)&W2[((cg * 3 + n) * 24 + c * 4 + ks) * 512 + (lane << 3)];
#pragma unroll
            for (int m = 0; m < 2; ++m)
#pragma unroll
            for (int n = 0; n < 3; ++n)
                acc2[m][n] = __builtin_amdgcn_mfma_f32_16x16x32_bf16(a[m], bb[n], acc2[m][n], 0, 0, 0);
        }
        __syncthreads();   // next FC1 may overwrite the buf we just read
    }

    // epilogue: bias + residual, in-place (nt RMW)
#pragma unroll
    for (int n = 0; n < 3; ++n) {
        int col = cg * 48 + n * 16 + l15;
        float bb2 = b2[col];
#pragma unroll
        for (int m = 0; m < 2; ++m)
#pragma unroll
        for (int r = 0; r < 4; ++r) {
            int tok = mq * 32 + m * 16 + (l4 << 2) + r;
            size_t idx = (tok0 + tok) * 192 + col;
            float pr = NTL(&o1[idx]);
            NTS(acc2[m][n][r] + bb2 + pr, &o1[idx]);
        }
    }
}

// ---------------- launch ----------------------------------------------------
extern "C" void kernel_launch(void* const* d_in, const int* in_sizes, int n_in,
                              void* d_out, int out_size, void* d_ws, size_t ws_size,
                              hipStream_t stream) {
    const float* x     = (const float*)d_in[0];
    const float* n1g   = (const float*)d_in[1];
    const float* n1b   = (const float*)d_in[2];
    const float* qkvw  = (const float*)d_in[3];
    const float* qkvb  = (const float*)d_in[4];
    const float* projw = (const float*)d_in[5];
    const float* projb = (const float*)d_in[6];
    const float* rpb   = (const float*)d_in[7];
    const float* n2g   = (const float*)d_in[8];
    const float* n2b   = (const float*)d_in[9];
    const float* fc1w  = (const float*)d_in[10];
    const float* fc1b  = (const float*)d_in[11];
    const float* fc2w  = (const float*)d_in[12];
    const float* fc2b  = (const float*)d_in[13];

    float* o1 = (float*)d_out;         // residual stream lives in d_out
    bf16* wsb = (bf16*)d_ws;           // 884736 B of bf16 weights (frag order)
    (void)ws_size; (void)in_sizes; (void)n_in; (void)out_size;

    w_cvt<<<216, 256, 0, stream>>>(qkvw, projw, fc1w, fc2w, wsb);
    k_win<<<2048, 1024, 0, stream>>>(x, n1g, n1b, wsb, qkvb, rpb, projb, o1);
    s_mlp<<<1024, 1024, 0, stream>>>(o1, n2g, n2b, wsb, fc1b, fc2b);
}